// Round 26
// baseline (448.254 us; speedup 1.0000x reference)
//
#include <hip/hip_runtime.h>

// S4MaskNet: 2-layer S4, B=8, D=256, L=2048, N=32. Inputs f32, OUTPUT f32.
// r26: GEMM family restructured to 32 KB LDS (BK=128 half-tile phases) ->
// occupancy 2->4 blocks/CU (8->16 waves/CU). r25 analysis: pipeline is
// per-kernel latency-bound (441us vs 68us pure-BW floor); gemm2's 83MB
// WRITE is upstream L2 writeback attribution, not store amplification.
// Rest identical to r25.

#define BSZ 8
#define DM 256
#define LSEQ 2048
#define NST 32
#define TC 64
#define NCH 32
#define TOK (BSZ*LSEQ)
#define NL 2

typedef __attribute__((ext_vector_type(8))) short bf16x8;
typedef __attribute__((ext_vector_type(4))) float f32x4;
typedef unsigned short ushort_t;

__device__ __forceinline__ float b2f(unsigned short v) {
    unsigned int u = ((unsigned int)v) << 16;
    float f;
    __builtin_memcpy(&f, &u, 4);
    return f;
}
__device__ __forceinline__ unsigned short f2b(float f) {
    unsigned int u;
    __builtin_memcpy(&u, &f, 4);
    unsigned int r = (u + 0x7FFFu + ((u >> 16) & 1u)) >> 16;   // RNE
    return (unsigned short)r;
}
__device__ __forceinline__ float gelu_f(float z) {
    float x = z * 0.70710678118654752f;
    float ax = fabsf(x);
    float t = 1.0f / (1.0f + 0.3275911f * ax);
    float poly = t * (0.254829592f + t * (-0.284496736f + t * (1.421413741f +
                 t * (-1.453152027f + t * 1.061405429f))));
    float erfax = 1.0f - poly * expf(-ax * ax);
    float er = (x < 0.0f) ? -erfax : erfax;
    return 0.5f * z * (1.0f + er);
}

// ---- setup: dtA, lambda, lambda^TC, CB ----
__global__ void k_setup_modes(const float* log_dt, const float* Alr, const float* Aim,
                              const float* Bre, const float* Bim,
                              const float* Cre, const float* Cim,
                              float2* dtA, float2* lam, float2* lamT, float2* CB) {
    int idx = blockIdx.x * blockDim.x + threadIdx.x;
    if (idx >= NL * DM * NST) return;
    int h = (idx >> 5) & (DM - 1);
    int i = idx >> 13;
    float dt  = expf(log_dt[i * DM + h]);
    float Are = -expf(Alr[idx]);
    float Ai  = Aim[idx];
    float dr = dt * Are, di = dt * Ai;
    float er = expf(dr);
    float lr = er * cosf(di), li = er * sinf(di);
    float inv = 1.0f / (Are * Are + Ai * Ai);
    float e1r = lr - 1.0f, e1i = li;
    float tr = (e1r * Are + e1i * Ai) * inv;
    float ti = (e1i * Are - e1r * Ai) * inv;
    float br = Bre[idx], bi = Bim[idx];
    float dBr = br * tr - bi * ti, dBi = br * ti + bi * tr;
    float cr = Cre[idx], ci = Cim[idx];
    dtA[idx] = make_float2(dr, di);
    lam[idx] = make_float2(lr, li);
    CB[idx]  = make_float2(cr * dBr - ci * dBi, cr * dBi + ci * dBr);
    float pr = lr, pi = li;
    for (int s = 0; s < 6; ++s) { float nr = pr * pr - pi * pi; pi = 2.f * pr * pi; pr = nr; }
    lamT[idx] = make_float2(pr, pi);
}

// ---- weight convert+transpose ----
__global__ void k_wcvt(const float* src, ushort_t* dst, int N) {
    int idx = blockIdx.x * 256 + threadIdx.x;
    if (idx >= N * 256) return;
    int n = idx >> 8, k = idx & 255;
    dst[idx] = f2b(src[(size_t)k * N + n]);
}

// ---- fused weight Wc = s4oW@lin1W ----
__global__ void k_wc_fuse(const float* Wa, const float* Wb, ushort_t* WBc) {
    int c = blockIdx.x;
    int r = threadIdx.x;
    const float* ar = Wa + (size_t)r * 256;
    float s = 0.f;
    for (int k = 0; k < 256; ++k) s = fmaf(ar[k], Wb[(size_t)k * 256 + c], s);
    WBc[(size_t)c * 256 + r] = f2b(s);
}
__global__ void k_bc_fuse(const float* s4ob, const float* Wb, const float* lin1b,
                          float* bc) {
    int c = threadIdx.x;
    float s = lin1b[c];
    for (int k = 0; k < 256; ++k) s = fmaf(s4ob[k], Wb[(size_t)k * 256 + c], s);
    bc[c] = s;
}

// ---- chunk tables ----
__global__ void k_setup_wk(const float2* dtA_l, const float2* lam_l, const float2* CB_l,
                           float* Ktab, float2* Wtab) {
    int idx = blockIdx.x * blockDim.x + threadIdx.x;
    if (idx >= DM * TC) return;
    int t = idx & (TC - 1);
    int h = idx >> 6;
    int base = h * NST;
    float ft = (float)t;
    float Ks = 0.f;
    for (int n = 0; n < NST; ++n) {
        float2 d = dtA_l[base + n]; float2 l1 = lam_l[base + n]; float2 cb = CB_l[base + n];
        float er = expf(d.x * ft);
        float cs = cosf(d.y * ft), sn = sinf(d.y * ft);
        float ltr = er * cs, lti = er * sn;
        Ks += cb.x * ltr - cb.y * lti;
        float p1r = ltr * l1.x - lti * l1.y, p1i = ltr * l1.y + lti * l1.x;
        Wtab[(h * NST + n) * TC + t] =
            make_float2(cb.x * p1r - cb.y * p1i, cb.x * p1i + cb.y * p1r);
    }
    Ktab[idx] = 2.f * Ks;
}

// ---- x [B, D, L] f32 -> o [B, L, D] bf16 ----
__global__ void k_transpose_in(const float* x, ushort_t* o) {
    __shared__ float tile[32][33];
    int b = blockIdx.z;
    int l0 = blockIdx.x * 32, d0 = blockIdx.y * 32;
    int tx = threadIdx.x, ty = threadIdx.y;
    for (int k = 0; k < 4; ++k)
        tile[ty + 8 * k][tx] = x[((size_t)b * DM + d0 + ty + 8 * k) * LSEQ + l0 + tx];
    __syncthreads();
    for (int k = 0; k < 4; ++k)
        o[((size_t)b * LSEQ + l0 + ty + 8 * k) * DM + d0 + tx] = f2b(tile[tx][ty + 8 * k]);
}

// ---- bf16 transposes (LDS-tiled) ----
__global__ void k_tr_t2h(const ushort_t* src, ushort_t* dst) {
    __shared__ float tile[32][33];
    int b = blockIdx.z;
    int l0 = blockIdx.x * 32, d0 = blockIdx.y * 32;
    int tx = threadIdx.x, ty = threadIdx.y;
    for (int k = 0; k < 4; ++k)
        tile[ty + 8 * k][tx] =
            b2f(src[((size_t)b * LSEQ + l0 + ty + 8 * k) * DM + d0 + tx]);
    __syncthreads();
    for (int k = 0; k < 4; ++k)
        dst[((size_t)b * DM + d0 + ty + 8 * k) * LSEQ + l0 + tx] =
            f2b(tile[tx][ty + 8 * k]);
}
__global__ void k_tr_h2t(const ushort_t* src, ushort_t* dst) {
    __shared__ float tile[32][33];
    int b = blockIdx.z;
    int l0 = blockIdx.x * 32, d0 = blockIdx.y * 32;
    int tx = threadIdx.x, ty = threadIdx.y;
    for (int k = 0; k < 4; ++k)
        tile[ty + 8 * k][tx] =
            b2f(src[((size_t)b * DM + d0 + ty + 8 * k) * LSEQ + l0 + tx]);
    __syncthreads();
    for (int k = 0; k < 4; ++k)
        dst[((size_t)b * LSEQ + l0 + ty + 8 * k) * DM + d0 + tx] =
            f2b(tile[tx][ty + 8 * k]);
}

// ---- layernorm (token-major) ----
__global__ void k_layernorm(const ushort_t* src, ushort_t* dst,
                            const float* g, const float* bb) {
    __shared__ float r1[DM];
    __shared__ float r2[DM];
    int tok = blockIdx.x;
    int d = threadIdx.x;
    float v = b2f(src[(size_t)tok * DM + d]);
    r1[d] = v;
    r2[d] = v * v;
    __syncthreads();
    for (int s = DM / 2; s > 0; s >>= 1) {
        if (d < s) { r1[d] += r1[d + s]; r2[d] += r2[d + s]; }
        __syncthreads();
    }
    float m = r1[0] * (1.0f / DM);
    float var = r2[0] * (1.0f / DM) - m * m;
    float inv = rsqrtf(var + 1e-5f);
    dst[(size_t)tok * DM + d] = f2b((v - m) * inv * g[d] + bb[d]);
}

// ---- chunk states from uT ----
__global__ void k_chunk_states(const ushort_t* uT, const float2* lam_l, float2* P) {
    int n = threadIdx.x & 31, hs = threadIdx.x >> 5;
    int c = blockIdx.x, h = blockIdx.y * 8 + hs, b = blockIdx.z;
    float2 lm = lam_l[h * NST + n];
    float sr = 0.f, si = 0.f;
    const ushort_t* up = uT + ((size_t)b * DM + h) * LSEQ + c * TC;
#pragma unroll 8
    for (int t = 0; t < TC; ++t) {
        float u = b2f(up[t]);
        float nr = fmaf(lm.x, sr, fmaf(-lm.y, si, u));
        float ni = fmaf(lm.x, si, lm.y * sr);
        sr = nr; si = ni;
    }
    P[(((size_t)b * DM + h) * NCH + c) * NST + n] = make_float2(sr, si);
}

// ---- scan ----
__global__ void k_chunk_scan(const float2* lamT_l, float2* P) {
    int idx = blockIdx.x * blockDim.x + threadIdx.x;
    if (idx >= BSZ * DM * NST) return;
    int n = idx & 31, h = (idx >> 5) & 255, b = idx >> 13;
    float2 lT = lamT_l[h * NST + n];
    float hr = 0.f, hi = 0.f;
    float2* base = P + (((size_t)b * DM + h) * NCH) * NST + n;
    for (int c = 0; c < NCH; ++c) {
        float2 p = base[(size_t)c * NST];
        base[(size_t)c * NST] = make_float2(hr, hi);
        float nr = fmaf(lT.x, hr, fmaf(-lT.y, hi, p.x));
        float ni = fmaf(lT.x, hi, fmaf(lT.y, hr, p.y));
        hr = nr; hi = ni;
    }
}

// ---- conv via MFMA; writes h-major GT ----
__global__ void k_conv_mfma(const ushort_t* uT, ushort_t* GT, const float* Ktab,
                            const float2* Wtab, const float2* P, const float* Dp_l) {
    __shared__ ushort_t As[64][128];
    __shared__ ushort_t Bs[256][128];
    int h = blockIdx.x;
    int tid = threadIdx.x;
    int wv = tid >> 6, l = tid & 63;
    for (int idx = tid; idx < 64 * 128; idx += 256) {
        int r = idx >> 7, e = idx & 127;
        float v;
        if (e < 64) {
            int d = r - e;
            v = (d >= 0) ? Ktab[h * TC + d] : 0.f;
        } else {
            int j = e - 64;
            float2 wc = Wtab[((size_t)h * NST + (j >> 1)) * TC + r];
            v = (j & 1) ? -2.f * wc.y : 2.f * wc.x;
        }
        As[r][e ^ ((r & 7) << 3)] = f2b(v);
    }
    for (int idx = tid; idx < 256 * 8; idx += 256) {
        int row = idx >> 3, ch = (idx & 7) * 8;
        int b = row >> 5, c = row & 31;
        bf16x8 v = *(const bf16x8*)(uT + ((size_t)b * DM + h) * LSEQ + c * TC + ch);
        *(bf16x8*)(&Bs[row][ch ^ ((row & 7) << 3)]) = v;
    }
    for (int idx = tid; idx < 256 * 32; idx += 256) {
        int row = idx >> 5, n = idx & 31;
        int b = row >> 5, c = row & 31;
        float2 s = P[(((size_t)b * DM + h) * NCH + c) * NST + n];
        int x = (row & 7) << 3;
        Bs[row][(64 + 2 * n) ^ x]     = f2b(s.x);
        Bs[row][(64 + 2 * n + 1) ^ x] = f2b(s.y);
    }
    __syncthreads();
    int lr = l & 15, lk = (l >> 4) * 8;
    int ax = (lr & 7) << 3;
    f32x4 acc[16];
#pragma unroll
    for (int i = 0; i < 16; ++i) acc[i] = (f32x4){0.f, 0.f, 0.f, 0.f};
#pragma unroll
    for (int k0 = 0; k0 < 128; k0 += 32) {
        bf16x8 a = *(const bf16x8*)(&As[wv * 16 + lr][(lk + k0) ^ ax]);
#pragma unroll
        for (int nt = 0; nt < 16; ++nt) {
            bf16x8 b = *(const bf16x8*)(&Bs[nt * 16 + lr][(lk + k0) ^ ax]);
            acc[nt] = __builtin_amdgcn_mfma_f32_16x16x32_bf16(a, b, acc[nt], 0, 0, 0);
        }
    }
    float dp = Dp_l[h];
#pragma unroll
    for (int nt = 0; nt < 16; ++nt) {
        int bc = nt * 16 + (l & 15);
        int b = bc >> 5, c = bc & 31;
        int bx = (bc & 7) << 3;
#pragma unroll
        for (int r = 0; r < 4; ++r) {
            int t = wv * 16 + (l >> 4) * 4 + r;
            float uv = b2f(Bs[bc][t ^ bx]);
            float z = acc[nt][r] + dp * uv;
            GT[((size_t)b * DM + h) * LSEQ + c * TC + t] = f2b(gelu_f(z));
        }
    }
}

// ==== 32 KB LDS MFMA GEMM (BK=128 half-tile phases) ====
__device__ __forceinline__ void stage_half(const ushort_t* src, int row0, int koff,
                                           ushort_t (*dst)[128], int tid) {
    for (int idx = tid; idx < 64 * 16; idx += 256) {
        int r = idx >> 4, ch = (idx & 15) * 8;
        bf16x8 v = *(const bf16x8*)(src + (size_t)(row0 + r) * 256 + koff + ch);
        *(bf16x8*)(&dst[r][ch ^ ((r & 7) << 3)]) = v;
    }
}
__device__ __forceinline__ void mma_half(const ushort_t (*As)[128],
                                         const ushort_t (*Bs)[128],
                                         int wv, int l, f32x4* acc) {
    int lr = l & 15, lk = (l >> 4) * 8;
    int ax = (lr & 7) << 3;
#pragma unroll
    for (int k0 = 0; k0 < 128; k0 += 32) {
        bf16x8 a  = *(const bf16x8*)(&As[wv * 16 + lr][(lk + k0) ^ ax]);
        bf16x8 b0 = *(const bf16x8*)(&Bs[lr]          [(lk + k0) ^ ax]);
        bf16x8 b1 = *(const bf16x8*)(&Bs[16 + lr]     [(lk + k0) ^ ax]);
        bf16x8 b2 = *(const bf16x8*)(&Bs[32 + lr]     [(lk + k0) ^ ax]);
        bf16x8 b3 = *(const bf16x8*)(&Bs[48 + lr]     [(lk + k0) ^ ax]);
        acc[0] = __builtin_amdgcn_mfma_f32_16x16x32_bf16(a, b0, acc[0], 0, 0, 0);
        acc[1] = __builtin_amdgcn_mfma_f32_16x16x32_bf16(a, b1, acc[1], 0, 0, 0);
        acc[2] = __builtin_amdgcn_mfma_f32_16x16x32_bf16(a, b2, acc[2], 0, 0, 0);
        acc[3] = __builtin_amdgcn_mfma_f32_16x16x32_bf16(a, b3, acc[3], 0, 0, 0);
    }
}
__device__ __forceinline__ void xcd_map(int* m0, int* n0) {
    int flat = blockIdx.y * gridDim.x + blockIdx.x;
    int xcd = flat & 7;
    int wl = flat >> 3;
    int nt = gridDim.y;
    int n_t = wl % nt;
    int m_t = xcd * (gridDim.x >> 3) + wl / nt;
    *m0 = m_t * 64;
    *n0 = n_t * 64;
}
#define OTP 66
__device__ __forceinline__ void epi_store(float* Ot, int wv, int l, f32x4* acc) {
    int lrow = wv * 16 + (l >> 4) * 4;
    int lcol = l & 15;
#pragma unroll
    for (int nt = 0; nt < 4; ++nt)
#pragma unroll
        for (int r = 0; r < 4; ++r)
            Ot[(lrow + r) * OTP + lcol + nt * 16] = acc[nt][r];
}

__global__ void k_gemm_mfma(const ushort_t* A, const ushort_t* WBt,
                            const float* bias, const ushort_t* res,
                            ushort_t* C, int N, int flags) {
    __shared__ ushort_t SM[32768];   // 32 KB: As 16KB + Bs 16KB; Ot aliases
    ushort_t (*As)[128] = (ushort_t(*)[128])SM;
    ushort_t (*Bs)[128] = (ushort_t(*)[128])(SM + 8192);
    int m0, n0;
    xcd_map(&m0, &n0);
    int tid = threadIdx.x;
    int wv = tid >> 6, l = tid & 63;
    f32x4 acc[4] = {{0,0,0,0},{0,0,0,0},{0,0,0,0},{0,0,0,0}};
#pragma unroll
    for (int kh = 0; kh < 2; ++kh) {
        stage_half(A, m0, kh * 128, As, tid);
        stage_half(WBt, n0, kh * 128, Bs, tid);
        __syncthreads();
        mma_half(As, Bs, wv, l, acc);
        __syncthreads();
    }
    float* Ot = (float*)SM;
    epi_store(Ot, wv, l, acc);
    __syncthreads();
    int row = tid >> 2, cs = (tid & 3) * 16;
    int m = m0 + row;
    ushort_t ov[16];
#pragma unroll
    for (int j = 0; j < 16; ++j) {
        float v = Ot[row * OTP + cs + j] + bias[n0 + cs + j];
        if (res) v += b2f(res[(size_t)m * DM + n0 + cs + j]);
        if (flags & 1) v = gelu_f(v);
        if (flags & 8) v = fmaxf(v, 0.0f);
        ov[j] = f2b(v);
    }
    *(bf16x8*)(C + (size_t)m * N + n0 + cs)     = *(bf16x8*)(ov);
    *(bf16x8*)(C + (size_t)m * N + n0 + cs + 8) = *(bf16x8*)(ov + 8);
}

__global__ void k_gemm2_mfma(const ushort_t* Aa, const ushort_t* WBa,
                             const ushort_t* Ab, const ushort_t* WBb,
                             const float* biasA, const float* biasB,
                             ushort_t* C, int N, int flags) {
    __shared__ ushort_t SM[32768];
    ushort_t (*As)[128] = (ushort_t(*)[128])SM;
    ushort_t (*Bs)[128] = (ushort_t(*)[128])(SM + 8192);
    int m0, n0;
    xcd_map(&m0, &n0);
    int tid = threadIdx.x;
    int wv = tid >> 6, l = tid & 63;
    f32x4 acc[4] = {{0,0,0,0},{0,0,0,0},{0,0,0,0},{0,0,0,0}};
#pragma unroll
    for (int ph = 0; ph < 4; ++ph) {
        const ushort_t* Ax = (ph < 2) ? Aa : Ab;
        const ushort_t* Wx = (ph < 2) ? WBa : WBb;
        int kh = ph & 1;
        stage_half(Ax, m0, kh * 128, As, tid);
        stage_half(Wx, n0, kh * 128, Bs, tid);
        __syncthreads();
        mma_half(As, Bs, wv, l, acc);
        __syncthreads();
    }
    float* Ot = (float*)SM;
    epi_store(Ot, wv, l, acc);
    __syncthreads();
    int row = tid >> 2, cs = (tid & 3) * 16;
    int m = m0 + row;
    ushort_t ov[16];
#pragma unroll
    for (int j = 0; j < 16; ++j) {
        float v = Ot[row * OTP + cs + j] + biasA[n0 + cs + j] + biasB[n0 + cs + j];
        if (flags & 8) v = fmaxf(v, 0.0f);
        ov[j] = f2b(v);
    }
    *(bf16x8*)(C + (size_t)m * N + n0 + cs)     = *(bf16x8*)(ov);
    *(bf16x8*)(C + (size_t)m * N + n0 + cs + 8) = *(bf16x8*)(ov + 8);
}

// ---- final: F [B,L,512] bf16 -> out [2,B,256,L] f32 ----
__global__ void k_final_out(const ushort_t* F, float* out) {
    __shared__ float tile[32][33];
    int b = blockIdx.z;
    int l0 = blockIdx.x * 32, c0 = blockIdx.y * 32;
    int tx = threadIdx.x, ty = threadIdx.y;
    for (int k = 0; k < 4; ++k)
        tile[ty + 8 * k][tx] = b2f(F[((size_t)(b * LSEQ + l0 + ty + 8 * k)) * 512 + c0 + tx]);
    __syncthreads();
    for (int k = 0; k < 4; ++k) {
        int cg = c0 + ty + 8 * k;
        int s = cg >> 8, cc = cg & 255;
        out[(((size_t)s * BSZ + b) * DM + cc) * LSEQ + l0 + tx] = tile[tx][ty + 8 * k];
    }
}

// ---- launcher ----
extern "C" void kernel_launch(void* const* d_in, const int* in_sizes, int n_in,
                              void* d_out, int out_size, void* d_ws, size_t ws_size,
                              hipStream_t stream) {
    (void)in_sizes; (void)n_in; (void)out_size;
    float* out = (float*)d_out;

    const float* x      = (const float*)d_in[0];
    const float* ln_g   = (const float*)d_in[1];
    const float* ln_b   = (const float*)d_in[2];
    const float* log_dt = (const float*)d_in[3];
    const float* Alr    = (const float*)d_in[4];
    const float* Aim    = (const float*)d_in[5];
    const float* Bre    = (const float*)d_in[6];
    const float* Bim    = (const float*)d_in[7];
    const float* Cre    = (const float*)d_in[8];
    const float* Cim    = (const float*)d_in[9];
    const float* Dp     = (const float*)d_in[10];
    const float* s4oW   = (const float*)d_in[11];
    const float* s4ob   = (const float*)d_in[12];
    const float* lin1W  = (const float*)d_in[13];
    const float* lin1b  = (const float*)d_in[14];
    const float* lin2W  = (const float*)d_in[15];
    const float* lin2b  = (const float*)d_in[16];
    const float* headW[2] = {(const float*)d_in[17], (const float*)d_in[21]};
    const float* headb[2] = {(const float*)d_in[18], (const float*)d_in[22]};
    const float* projW[2] = {(const float*)d_in[19], (const float*)d_in[23]};
    const float* projb[2] = {(const float*)d_in[20], (const float*)d_in[24]};

    char* w = (char*)d_ws;
    ushort_t* A0 = (ushort_t*)w;  w += (size_t)TOK * DM * 2;
    ushort_t* A1 = (ushort_t*)w;  w += (size_t)TOK * DM * 2;
    ushort_t* A2 = (ushort_t*)w;  w += (size_t)TOK * DM * 2;
    float2* dtA  = (float2*)w;    w += (size_t)NL * DM * NST * 8;
    float2* lam  = (float2*)w;    w += (size_t)NL * DM * NST * 8;
    float2* lamT = (float2*)w;    w += (size_t)NL * DM * NST * 8;
    float2* CB   = (float2*)w;    w += (size_t)NL * DM * NST * 8;
    float2* P    = (float2*)w;    w += (size_t)BSZ * DM * NCH * NST * 8;  // 16 MiB
    float2* Wtab = (float2*)w;    w += (size_t)DM * NST * TC * 8;
    float*  KtabC = (float*)w;    w += (size_t)DM * TC * 4;
    ushort_t* wb = (ushort_t*)w;  w += (size_t)655360 * 2;
    float*  bc   = (float*)w;     w += 512 * 4;
    if ((size_t)(w - (char*)d_ws) > ws_size) return;   // ~46 MiB (proven)
    ushort_t* F = (ushort_t*)P;

    ushort_t* WB_lin2[2] = {wb + 0,      wb + 65536};
    ushort_t* WB_head0   = wb + 131072;
    ushort_t* WB_proj0   = wb + 196608;
    ushort_t* WB_head1   = wb + 262144;
    ushort_t* WB_proj1   = wb + 393216;
    ushort_t* WBc[2]     = {wb + 524288, wb + 589824};

    k_setup_modes<<<NL * DM * NST / 256, 256, 0, stream>>>(
        log_dt, Alr, Aim, Bre, Bim, Cre, Cim, dtA, lam, lamT, CB);
    for (int i = 0; i < NL; ++i) {
        size_t wf = (size_t)i * DM * DM;
        k_wcvt<<<256, 256, 0, stream>>>(lin2W + wf, WB_lin2[i], DM);
        k_wc_fuse<<<256, 256, 0, stream>>>(s4oW + wf, lin1W + wf, WBc[i]);
        k_bc_fuse<<<1, 256, 0, stream>>>(s4ob + i * DM, lin1W + wf, lin1b + i * DM,
                                         bc + i * 256);
    }
    k_wcvt<<<256, 256, 0, stream>>>(headW[0], WB_head0, DM);
    k_wcvt<<<256, 256, 0, stream>>>(projW[0], WB_proj0, DM);
    k_wcvt<<<512, 256, 0, stream>>>(headW[1], WB_head1, 2 * DM);
    k_wcvt<<<512, 256, 0, stream>>>(projW[1], WB_proj1, 2 * DM);
    {
        dim3 gt(LSEQ / 32, DM / 32, BSZ);
        dim3 bt(32, 8);
        k_transpose_in<<<gt, bt, 0, stream>>>(x, A0);
    }

    dim3 gg(TOK / 64, DM / 64);
    dim3 gtr(LSEQ / 32, DM / 32, BSZ);
    dim3 btr(32, 8);
    for (int i = 0; i < NL; ++i) {
        size_t off = (size_t)i * DM * NST;

        k_layernorm<<<TOK, DM, 0, stream>>>(A0, A1, ln_g + (2 * i) * DM,
                                            ln_b + (2 * i) * DM);
        k_tr_t2h<<<gtr, btr, 0, stream>>>(A1, A2);          // A2 = uT
        k_setup_wk<<<DM * TC / 128, 128, 0, stream>>>(dtA + off, lam + off,
                                                      CB + off, KtabC, Wtab);
        {
            dim3 gs(NCH, DM / 8, BSZ);
            k_chunk_states<<<gs, 256, 0, stream>>>(A2, lam + off, P);
        }
        k_chunk_scan<<<BSZ * DM * NST / 256, 256, 0, stream>>>(lamT + off, P);
        k_conv_mfma<<<DM, 256, 0, stream>>>(A2, A1, KtabC, Wtab, P, Dp + i * DM);
        k_tr_h2t<<<gtr, btr, 0, stream>>>(A1, A2);          // A2 = G token-major
        // o1 = G@Wc + bc + res(A0) -> A1
        k_gemm_mfma<<<gg, 256, 0, stream>>>(A2, WBc[i], bc + i * 256, A0, A1, DM, 0);
        // LN2(A1) -> A0
        k_layernorm<<<TOK, DM, 0, stream>>>(A1, A0, ln_g + (2 * i + 1) * DM,
                                            ln_b + (2 * i + 1) * DM);
        // g2 = gelu(A0@lin2) -> A2
        k_gemm_mfma<<<gg, 256, 0, stream>>>(A0, WB_lin2[i], lin2b + i * DM, 0, A2, DM, 1);
        if (i == 0) {
            k_gemm2_mfma<<<gg, 256, 0, stream>>>(A2, WB_head0, A1, WB_proj0,
                                                 headb[0], projb[0], A0, DM, 0);
        } else {
            dim3 gh(TOK / 64, 2 * DM / 64);
            k_gemm2_mfma<<<gh, 256, 0, stream>>>(A2, WB_head1, A1, WB_proj1,
                                                 headb[1], projb[1], F, 2 * DM, 8);
        }
    }
    {
        dim3 gf(LSEQ / 32, 2 * DM / 32, BSZ);
        dim3 bf(32, 8);
        k_final_out<<<gf, bf, 0, stream>>>(F, out);
    }
}

// Round 27
// 408.842 us; speedup vs baseline: 1.0964x; 1.0964x over previous
//
#include <hip/hip_runtime.h>

// S4MaskNet: 2-layer S4, B=8, D=256, L=2048, N=32. Inputs f32, OUTPUT f32.
// r27: fixes r26's elements-vs-bytes bug -- SM[32768] ushort was 64 KB, so
// the occupancy experiment never ran (LDS_Block_Size stayed 65536, occ 18%).
// Now SM[16384] = 32 KB true: 5 blocks/CU (20 waves/CU, 2.5x). Everything
// else byte-identical to r26.

#define BSZ 8
#define DM 256
#define LSEQ 2048
#define NST 32
#define TC 64
#define NCH 32
#define TOK (BSZ*LSEQ)
#define NL 2

typedef __attribute__((ext_vector_type(8))) short bf16x8;
typedef __attribute__((ext_vector_type(4))) float f32x4;
typedef unsigned short ushort_t;

__device__ __forceinline__ float b2f(unsigned short v) {
    unsigned int u = ((unsigned int)v) << 16;
    float f;
    __builtin_memcpy(&f, &u, 4);
    return f;
}
__device__ __forceinline__ unsigned short f2b(float f) {
    unsigned int u;
    __builtin_memcpy(&u, &f, 4);
    unsigned int r = (u + 0x7FFFu + ((u >> 16) & 1u)) >> 16;   // RNE
    return (unsigned short)r;
}
__device__ __forceinline__ float gelu_f(float z) {
    float x = z * 0.70710678118654752f;
    float ax = fabsf(x);
    float t = 1.0f / (1.0f + 0.3275911f * ax);
    float poly = t * (0.254829592f + t * (-0.284496736f + t * (1.421413741f +
                 t * (-1.453152027f + t * 1.061405429f))));
    float erfax = 1.0f - poly * expf(-ax * ax);
    float er = (x < 0.0f) ? -erfax : erfax;
    return 0.5f * z * (1.0f + er);
}

// ---- setup: dtA, lambda, lambda^TC, CB ----
__global__ void k_setup_modes(const float* log_dt, const float* Alr, const float* Aim,
                              const float* Bre, const float* Bim,
                              const float* Cre, const float* Cim,
                              float2* dtA, float2* lam, float2* lamT, float2* CB) {
    int idx = blockIdx.x * blockDim.x + threadIdx.x;
    if (idx >= NL * DM * NST) return;
    int h = (idx >> 5) & (DM - 1);
    int i = idx >> 13;
    float dt  = expf(log_dt[i * DM + h]);
    float Are = -expf(Alr[idx]);
    float Ai  = Aim[idx];
    float dr = dt * Are, di = dt * Ai;
    float er = expf(dr);
    float lr = er * cosf(di), li = er * sinf(di);
    float inv = 1.0f / (Are * Are + Ai * Ai);
    float e1r = lr - 1.0f, e1i = li;
    float tr = (e1r * Are + e1i * Ai) * inv;
    float ti = (e1i * Are - e1r * Ai) * inv;
    float br = Bre[idx], bi = Bim[idx];
    float dBr = br * tr - bi * ti, dBi = br * ti + bi * tr;
    float cr = Cre[idx], ci = Cim[idx];
    dtA[idx] = make_float2(dr, di);
    lam[idx] = make_float2(lr, li);
    CB[idx]  = make_float2(cr * dBr - ci * dBi, cr * dBi + ci * dBr);
    float pr = lr, pi = li;
    for (int s = 0; s < 6; ++s) { float nr = pr * pr - pi * pi; pi = 2.f * pr * pi; pr = nr; }
    lamT[idx] = make_float2(pr, pi);
}

// ---- weight convert+transpose ----
__global__ void k_wcvt(const float* src, ushort_t* dst, int N) {
    int idx = blockIdx.x * 256 + threadIdx.x;
    if (idx >= N * 256) return;
    int n = idx >> 8, k = idx & 255;
    dst[idx] = f2b(src[(size_t)k * N + n]);
}

// ---- fused weight Wc = s4oW@lin1W ----
__global__ void k_wc_fuse(const float* Wa, const float* Wb, ushort_t* WBc) {
    int c = blockIdx.x;
    int r = threadIdx.x;
    const float* ar = Wa + (size_t)r * 256;
    float s = 0.f;
    for (int k = 0; k < 256; ++k) s = fmaf(ar[k], Wb[(size_t)k * 256 + c], s);
    WBc[(size_t)c * 256 + r] = f2b(s);
}
__global__ void k_bc_fuse(const float* s4ob, const float* Wb, const float* lin1b,
                          float* bc) {
    int c = threadIdx.x;
    float s = lin1b[c];
    for (int k = 0; k < 256; ++k) s = fmaf(s4ob[k], Wb[(size_t)k * 256 + c], s);
    bc[c] = s;
}

// ---- chunk tables ----
__global__ void k_setup_wk(const float2* dtA_l, const float2* lam_l, const float2* CB_l,
                           float* Ktab, float2* Wtab) {
    int idx = blockIdx.x * blockDim.x + threadIdx.x;
    if (idx >= DM * TC) return;
    int t = idx & (TC - 1);
    int h = idx >> 6;
    int base = h * NST;
    float ft = (float)t;
    float Ks = 0.f;
    for (int n = 0; n < NST; ++n) {
        float2 d = dtA_l[base + n]; float2 l1 = lam_l[base + n]; float2 cb = CB_l[base + n];
        float er = expf(d.x * ft);
        float cs = cosf(d.y * ft), sn = sinf(d.y * ft);
        float ltr = er * cs, lti = er * sn;
        Ks += cb.x * ltr - cb.y * lti;
        float p1r = ltr * l1.x - lti * l1.y, p1i = ltr * l1.y + lti * l1.x;
        Wtab[(h * NST + n) * TC + t] =
            make_float2(cb.x * p1r - cb.y * p1i, cb.x * p1i + cb.y * p1r);
    }
    Ktab[idx] = 2.f * Ks;
}

// ---- x [B, D, L] f32 -> o [B, L, D] bf16 ----
__global__ void k_transpose_in(const float* x, ushort_t* o) {
    __shared__ float tile[32][33];
    int b = blockIdx.z;
    int l0 = blockIdx.x * 32, d0 = blockIdx.y * 32;
    int tx = threadIdx.x, ty = threadIdx.y;
    for (int k = 0; k < 4; ++k)
        tile[ty + 8 * k][tx] = x[((size_t)b * DM + d0 + ty + 8 * k) * LSEQ + l0 + tx];
    __syncthreads();
    for (int k = 0; k < 4; ++k)
        o[((size_t)b * LSEQ + l0 + ty + 8 * k) * DM + d0 + tx] = f2b(tile[tx][ty + 8 * k]);
}

// ---- bf16 transposes (LDS-tiled) ----
__global__ void k_tr_t2h(const ushort_t* src, ushort_t* dst) {
    __shared__ float tile[32][33];
    int b = blockIdx.z;
    int l0 = blockIdx.x * 32, d0 = blockIdx.y * 32;
    int tx = threadIdx.x, ty = threadIdx.y;
    for (int k = 0; k < 4; ++k)
        tile[ty + 8 * k][tx] =
            b2f(src[((size_t)b * LSEQ + l0 + ty + 8 * k) * DM + d0 + tx]);
    __syncthreads();
    for (int k = 0; k < 4; ++k)
        dst[((size_t)b * DM + d0 + ty + 8 * k) * LSEQ + l0 + tx] =
            f2b(tile[tx][ty + 8 * k]);
}
__global__ void k_tr_h2t(const ushort_t* src, ushort_t* dst) {
    __shared__ float tile[32][33];
    int b = blockIdx.z;
    int l0 = blockIdx.x * 32, d0 = blockIdx.y * 32;
    int tx = threadIdx.x, ty = threadIdx.y;
    for (int k = 0; k < 4; ++k)
        tile[ty + 8 * k][tx] =
            b2f(src[((size_t)b * DM + d0 + ty + 8 * k) * LSEQ + l0 + tx]);
    __syncthreads();
    for (int k = 0; k < 4; ++k)
        dst[((size_t)b * LSEQ + l0 + ty + 8 * k) * DM + d0 + tx] =
            f2b(tile[tx][ty + 8 * k]);
}

// ---- layernorm (token-major) ----
__global__ void k_layernorm(const ushort_t* src, ushort_t* dst,
                            const float* g, const float* bb) {
    __shared__ float r1[DM];
    __shared__ float r2[DM];
    int tok = blockIdx.x;
    int d = threadIdx.x;
    float v = b2f(src[(size_t)tok * DM + d]);
    r1[d] = v;
    r2[d] = v * v;
    __syncthreads();
    for (int s = DM / 2; s > 0; s >>= 1) {
        if (d < s) { r1[d] += r1[d + s]; r2[d] += r2[d + s]; }
        __syncthreads();
    }
    float m = r1[0] * (1.0f / DM);
    float var = r2[0] * (1.0f / DM) - m * m;
    float inv = rsqrtf(var + 1e-5f);
    dst[(size_t)tok * DM + d] = f2b((v - m) * inv * g[d] + bb[d]);
}

// ---- chunk states from uT ----
__global__ void k_chunk_states(const ushort_t* uT, const float2* lam_l, float2* P) {
    int n = threadIdx.x & 31, hs = threadIdx.x >> 5;
    int c = blockIdx.x, h = blockIdx.y * 8 + hs, b = blockIdx.z;
    float2 lm = lam_l[h * NST + n];
    float sr = 0.f, si = 0.f;
    const ushort_t* up = uT + ((size_t)b * DM + h) * LSEQ + c * TC;
#pragma unroll 8
    for (int t = 0; t < TC; ++t) {
        float u = b2f(up[t]);
        float nr = fmaf(lm.x, sr, fmaf(-lm.y, si, u));
        float ni = fmaf(lm.x, si, lm.y * sr);
        sr = nr; si = ni;
    }
    P[(((size_t)b * DM + h) * NCH + c) * NST + n] = make_float2(sr, si);
}

// ---- scan ----
__global__ void k_chunk_scan(const float2* lamT_l, float2* P) {
    int idx = blockIdx.x * blockDim.x + threadIdx.x;
    if (idx >= BSZ * DM * NST) return;
    int n = idx & 31, h = (idx >> 5) & 255, b = idx >> 13;
    float2 lT = lamT_l[h * NST + n];
    float hr = 0.f, hi = 0.f;
    float2* base = P + (((size_t)b * DM + h) * NCH) * NST + n;
    for (int c = 0; c < NCH; ++c) {
        float2 p = base[(size_t)c * NST];
        base[(size_t)c * NST] = make_float2(hr, hi);
        float nr = fmaf(lT.x, hr, fmaf(-lT.y, hi, p.x));
        float ni = fmaf(lT.x, hi, fmaf(lT.y, hr, p.y));
        hr = nr; hi = ni;
    }
}

// ---- conv via MFMA; writes h-major GT ----
__global__ void k_conv_mfma(const ushort_t* uT, ushort_t* GT, const float* Ktab,
                            const float2* Wtab, const float2* P, const float* Dp_l) {
    __shared__ ushort_t As[64][128];
    __shared__ ushort_t Bs[256][128];
    int h = blockIdx.x;
    int tid = threadIdx.x;
    int wv = tid >> 6, l = tid & 63;
    for (int idx = tid; idx < 64 * 128; idx += 256) {
        int r = idx >> 7, e = idx & 127;
        float v;
        if (e < 64) {
            int d = r - e;
            v = (d >= 0) ? Ktab[h * TC + d] : 0.f;
        } else {
            int j = e - 64;
            float2 wc = Wtab[((size_t)h * NST + (j >> 1)) * TC + r];
            v = (j & 1) ? -2.f * wc.y : 2.f * wc.x;
        }
        As[r][e ^ ((r & 7) << 3)] = f2b(v);
    }
    for (int idx = tid; idx < 256 * 8; idx += 256) {
        int row = idx >> 3, ch = (idx & 7) * 8;
        int b = row >> 5, c = row & 31;
        bf16x8 v = *(const bf16x8*)(uT + ((size_t)b * DM + h) * LSEQ + c * TC + ch);
        *(bf16x8*)(&Bs[row][ch ^ ((row & 7) << 3)]) = v;
    }
    for (int idx = tid; idx < 256 * 32; idx += 256) {
        int row = idx >> 5, n = idx & 31;
        int b = row >> 5, c = row & 31;
        float2 s = P[(((size_t)b * DM + h) * NCH + c) * NST + n];
        int x = (row & 7) << 3;
        Bs[row][(64 + 2 * n) ^ x]     = f2b(s.x);
        Bs[row][(64 + 2 * n + 1) ^ x] = f2b(s.y);
    }
    __syncthreads();
    int lr = l & 15, lk = (l >> 4) * 8;
    int ax = (lr & 7) << 3;
    f32x4 acc[16];
#pragma unroll
    for (int i = 0; i < 16; ++i) acc[i] = (f32x4){0.f, 0.f, 0.f, 0.f};
#pragma unroll
    for (int k0 = 0; k0 < 128; k0 += 32) {
        bf16x8 a = *(const bf16x8*)(&As[wv * 16 + lr][(lk + k0) ^ ax]);
#pragma unroll
        for (int nt = 0; nt < 16; ++nt) {
            bf16x8 b = *(const bf16x8*)(&Bs[nt * 16 + lr][(lk + k0) ^ ax]);
            acc[nt] = __builtin_amdgcn_mfma_f32_16x16x32_bf16(a, b, acc[nt], 0, 0, 0);
        }
    }
    float dp = Dp_l[h];
#pragma unroll
    for (int nt = 0; nt < 16; ++nt) {
        int bc = nt * 16 + (l & 15);
        int b = bc >> 5, c = bc & 31;
        int bx = (bc & 7) << 3;
#pragma unroll
        for (int r = 0; r < 4; ++r) {
            int t = wv * 16 + (l >> 4) * 4 + r;
            float uv = b2f(Bs[bc][t ^ bx]);
            float z = acc[nt][r] + dp * uv;
            GT[((size_t)b * DM + h) * LSEQ + c * TC + t] = f2b(gelu_f(z));
        }
    }
}

// ==== 32 KB LDS MFMA GEMM (BK=128 half-tile phases) ====
__device__ __forceinline__ void stage_half(const ushort_t* src, int row0, int koff,
                                           ushort_t (*dst)[128], int tid) {
    for (int idx = tid; idx < 64 * 16; idx += 256) {
        int r = idx >> 4, ch = (idx & 15) * 8;
        bf16x8 v = *(const bf16x8*)(src + (size_t)(row0 + r) * 256 + koff + ch);
        *(bf16x8*)(&dst[r][ch ^ ((r & 7) << 3)]) = v;
    }
}
__device__ __forceinline__ void mma_half(const ushort_t (*As)[128],
                                         const ushort_t (*Bs)[128],
                                         int wv, int l, f32x4* acc) {
    int lr = l & 15, lk = (l >> 4) * 8;
    int ax = (lr & 7) << 3;
#pragma unroll
    for (int k0 = 0; k0 < 128; k0 += 32) {
        bf16x8 a  = *(const bf16x8*)(&As[wv * 16 + lr][(lk + k0) ^ ax]);
        bf16x8 b0 = *(const bf16x8*)(&Bs[lr]          [(lk + k0) ^ ax]);
        bf16x8 b1 = *(const bf16x8*)(&Bs[16 + lr]     [(lk + k0) ^ ax]);
        bf16x8 b2 = *(const bf16x8*)(&Bs[32 + lr]     [(lk + k0) ^ ax]);
        bf16x8 b3 = *(const bf16x8*)(&Bs[48 + lr]     [(lk + k0) ^ ax]);
        acc[0] = __builtin_amdgcn_mfma_f32_16x16x32_bf16(a, b0, acc[0], 0, 0, 0);
        acc[1] = __builtin_amdgcn_mfma_f32_16x16x32_bf16(a, b1, acc[1], 0, 0, 0);
        acc[2] = __builtin_amdgcn_mfma_f32_16x16x32_bf16(a, b2, acc[2], 0, 0, 0);
        acc[3] = __builtin_amdgcn_mfma_f32_16x16x32_bf16(a, b3, acc[3], 0, 0, 0);
    }
}
__device__ __forceinline__ void xcd_map(int* m0, int* n0) {
    int flat = blockIdx.y * gridDim.x + blockIdx.x;
    int xcd = flat & 7;
    int wl = flat >> 3;
    int nt = gridDim.y;
    int n_t = wl % nt;
    int m_t = xcd * (gridDim.x >> 3) + wl / nt;
    *m0 = m_t * 64;
    *n0 = n_t * 64;
}
#define OTP 66
__device__ __forceinline__ void epi_store(float* Ot, int wv, int l, f32x4* acc) {
    int lrow = wv * 16 + (l >> 4) * 4;
    int lcol = l & 15;
#pragma unroll
    for (int nt = 0; nt < 4; ++nt)
#pragma unroll
        for (int r = 0; r < 4; ++r)
            Ot[(lrow + r) * OTP + lcol + nt * 16] = acc[nt][r];
}

__global__ void k_gemm_mfma(const ushort_t* A, const ushort_t* WBt,
                            const float* bias, const ushort_t* res,
                            ushort_t* C, int N, int flags) {
    __shared__ ushort_t SM[16384];   // 32 KB TRUE: As 16KB + Bs 16KB; Ot aliases
    ushort_t (*As)[128] = (ushort_t(*)[128])SM;
    ushort_t (*Bs)[128] = (ushort_t(*)[128])(SM + 8192);
    int m0, n0;
    xcd_map(&m0, &n0);
    int tid = threadIdx.x;
    int wv = tid >> 6, l = tid & 63;
    f32x4 acc[4] = {{0,0,0,0},{0,0,0,0},{0,0,0,0},{0,0,0,0}};
#pragma unroll
    for (int kh = 0; kh < 2; ++kh) {
        stage_half(A, m0, kh * 128, As, tid);
        stage_half(WBt, n0, kh * 128, Bs, tid);
        __syncthreads();
        mma_half(As, Bs, wv, l, acc);
        __syncthreads();
    }
    float* Ot = (float*)SM;
    epi_store(Ot, wv, l, acc);
    __syncthreads();
    int row = tid >> 2, cs = (tid & 3) * 16;
    int m = m0 + row;
    ushort_t ov[16];
#pragma unroll
    for (int j = 0; j < 16; ++j) {
        float v = Ot[row * OTP + cs + j] + bias[n0 + cs + j];
        if (res) v += b2f(res[(size_t)m * DM + n0 + cs + j]);
        if (flags & 1) v = gelu_f(v);
        if (flags & 8) v = fmaxf(v, 0.0f);
        ov[j] = f2b(v);
    }
    *(bf16x8*)(C + (size_t)m * N + n0 + cs)     = *(bf16x8*)(ov);
    *(bf16x8*)(C + (size_t)m * N + n0 + cs + 8) = *(bf16x8*)(ov + 8);
}

__global__ void k_gemm2_mfma(const ushort_t* Aa, const ushort_t* WBa,
                             const ushort_t* Ab, const ushort_t* WBb,
                             const float* biasA, const float* biasB,
                             ushort_t* C, int N, int flags) {
    __shared__ ushort_t SM[16384];   // 32 KB TRUE
    ushort_t (*As)[128] = (ushort_t(*)[128])SM;
    ushort_t (*Bs)[128] = (ushort_t(*)[128])(SM + 8192);
    int m0, n0;
    xcd_map(&m0, &n0);
    int tid = threadIdx.x;
    int wv = tid >> 6, l = tid & 63;
    f32x4 acc[4] = {{0,0,0,0},{0,0,0,0},{0,0,0,0},{0,0,0,0}};
#pragma unroll
    for (int ph = 0; ph < 4; ++ph) {
        const ushort_t* Ax = (ph < 2) ? Aa : Ab;
        const ushort_t* Wx = (ph < 2) ? WBa : WBb;
        int kh = ph & 1;
        stage_half(Ax, m0, kh * 128, As, tid);
        stage_half(Wx, n0, kh * 128, Bs, tid);
        __syncthreads();
        mma_half(As, Bs, wv, l, acc);
        __syncthreads();
    }
    float* Ot = (float*)SM;
    epi_store(Ot, wv, l, acc);
    __syncthreads();
    int row = tid >> 2, cs = (tid & 3) * 16;
    int m = m0 + row;
    ushort_t ov[16];
#pragma unroll
    for (int j = 0; j < 16; ++j) {
        float v = Ot[row * OTP + cs + j] + biasA[n0 + cs + j] + biasB[n0 + cs + j];
        if (flags & 8) v = fmaxf(v, 0.0f);
        ov[j] = f2b(v);
    }
    *(bf16x8*)(C + (size_t)m * N + n0 + cs)     = *(bf16x8*)(ov);
    *(bf16x8*)(C + (size_t)m * N + n0 + cs + 8) = *(bf16x8*)(ov + 8);
}

// ---- final: F [B,L,512] bf16 -> out [2,B,256,L] f32 ----
__global__ void k_final_out(const ushort_t* F, float* out) {
    __shared__ float tile[32][33];
    int b = blockIdx.z;
    int l0 = blockIdx.x * 32, c0 = blockIdx.y * 32;
    int tx = threadIdx.x, ty = threadIdx.y;
    for (int k = 0; k < 4; ++k)
        tile[ty + 8 * k][tx] = b2f(F[((size_t)(b * LSEQ + l0 + ty + 8 * k)) * 512 + c0 + tx]);
    __syncthreads();
    for (int k = 0; k < 4; ++k) {
        int cg = c0 + ty + 8 * k;
        int s = cg >> 8, cc = cg & 255;
        out[(((size_t)s * BSZ + b) * DM + cc) * LSEQ + l0 + tx] = tile[tx][ty + 8 * k];
    }
}

// ---- launcher ----
extern "C" void kernel_launch(void* const* d_in, const int* in_sizes, int n_in,
                              void* d_out, int out_size, void* d_ws, size_t ws_size,
                              hipStream_t stream) {
    (void)in_sizes; (void)n_in; (void)out_size;
    float* out = (float*)d_out;

    const float* x      = (const float*)d_in[0];
    const float* ln_g   = (const float*)d_in[1];
    const float* ln_b   = (const float*)d_in[2];
    const float* log_dt = (const float*)d_in[3];
    const float* Alr    = (const float*)d_in[4];
    const float* Aim    = (const float*)d_in[5];
    const float* Bre    = (const float*)d_in[6];
    const float* Bim    = (const float*)d_in[7];
    const float* Cre    = (const float*)d_in[8];
    const float* Cim    = (const float*)d_in[9];
    const float* Dp     = (const float*)d_in[10];
    const float* s4oW   = (const float*)d_in[11];
    const float* s4ob   = (const float*)d_in[12];
    const float* lin1W  = (const float*)d_in[13];
    const float* lin1b  = (const float*)d_in[14];
    const float* lin2W  = (const float*)d_in[15];
    const float* lin2b  = (const float*)d_in[16];
    const float* headW[2] = {(const float*)d_in[17], (const float*)d_in[21]};
    const float* headb[2] = {(const float*)d_in[18], (const float*)d_in[22]};
    const float* projW[2] = {(const float*)d_in[19], (const float*)d_in[23]};
    const float* projb[2] = {(const float*)d_in[20], (const float*)d_in[24]};

    char* w = (char*)d_ws;
    ushort_t* A0 = (ushort_t*)w;  w += (size_t)TOK * DM * 2;
    ushort_t* A1 = (ushort_t*)w;  w += (size_t)TOK * DM * 2;
    ushort_t* A2 = (ushort_t*)w;  w += (size_t)TOK * DM * 2;
    float2* dtA  = (float2*)w;    w += (size_t)NL * DM * NST * 8;
    float2* lam  = (float2*)w;    w += (size_t)NL * DM * NST * 8;
    float2* lamT = (float2*)w;    w += (size_t)NL * DM * NST * 8;
    float2* CB   = (float2*)w;    w += (size_t)NL * DM * NST * 8;
    float2* P    = (float2*)w;    w += (size_t)BSZ * DM * NCH * NST * 8;  // 16 MiB
    float2* Wtab = (float2*)w;    w += (size_t)DM * NST * TC * 8;
    float*  KtabC = (float*)w;    w += (size_t)DM * TC * 4;
    ushort_t* wb = (ushort_t*)w;  w += (size_t)655360 * 2;
    float*  bc   = (float*)w;     w += 512 * 4;
    if ((size_t)(w - (char*)d_ws) > ws_size) return;   // ~46 MiB (proven)
    ushort_t* F = (ushort_t*)P;

    ushort_t* WB_lin2[2] = {wb + 0,      wb + 65536};
    ushort_t* WB_head0   = wb + 131072;
    ushort_t* WB_proj0   = wb + 196608;
    ushort_t* WB_head1   = wb + 262144;
    ushort_t* WB_proj1   = wb + 393216;
    ushort_t* WBc[2]     = {wb + 524288, wb + 589824};

    k_setup_modes<<<NL * DM * NST / 256, 256, 0, stream>>>(
        log_dt, Alr, Aim, Bre, Bim, Cre, Cim, dtA, lam, lamT, CB);
    for (int i = 0; i < NL; ++i) {
        size_t wf = (size_t)i * DM * DM;
        k_wcvt<<<256, 256, 0, stream>>>(lin2W + wf, WB_lin2[i], DM);
        k_wc_fuse<<<256, 256, 0, stream>>>(s4oW + wf, lin1W + wf, WBc[i]);
        k_bc_fuse<<<1, 256, 0, stream>>>(s4ob + i * DM, lin1W + wf, lin1b + i * DM,
                                         bc + i * 256);
    }
    k_wcvt<<<256, 256, 0, stream>>>(headW[0], WB_head0, DM);
    k_wcvt<<<256, 256, 0, stream>>>(projW[0], WB_proj0, DM);
    k_wcvt<<<512, 256, 0, stream>>>(headW[1], WB_head1, 2 * DM);
    k_wcvt<<<512, 256, 0, stream>>>(projW[1], WB_proj1, 2 * DM);
    {
        dim3 gt(LSEQ / 32, DM / 32, BSZ);
        dim3 bt(32, 8);
        k_transpose_in<<<gt, bt, 0, stream>>>(x, A0);
    }

    dim3 gg(TOK / 64, DM / 64);
    dim3 gtr(LSEQ / 32, DM / 32, BSZ);
    dim3 btr(32, 8);
    for (int i = 0; i < NL; ++i) {
        size_t off = (size_t)i * DM * NST;

        k_layernorm<<<TOK, DM, 0, stream>>>(A0, A1, ln_g + (2 * i) * DM,
                                            ln_b + (2 * i) * DM);
        k_tr_t2h<<<gtr, btr, 0, stream>>>(A1, A2);          // A2 = uT
        k_setup_wk<<<DM * TC / 128, 128, 0, stream>>>(dtA + off, lam + off,
                                                      CB + off, KtabC, Wtab);
        {
            dim3 gs(NCH, DM / 8, BSZ);
            k_chunk_states<<<gs, 256, 0, stream>>>(A2, lam + off, P);
        }
        k_chunk_scan<<<BSZ * DM * NST / 256, 256, 0, stream>>>(lamT + off, P);
        k_conv_mfma<<<DM, 256, 0, stream>>>(A2, A1, KtabC, Wtab, P, Dp + i * DM);
        k_tr_h2t<<<gtr, btr, 0, stream>>>(A1, A2);          // A2 = G token-major
        // o1 = G@Wc + bc + res(A0) -> A1
        k_gemm_mfma<<<gg, 256, 0, stream>>>(A2, WBc[i], bc + i * 256, A0, A1, DM, 0);
        // LN2(A1) -> A0
        k_layernorm<<<TOK, DM, 0, stream>>>(A1, A0, ln_g + (2 * i + 1) * DM,
                                            ln_b + (2 * i + 1) * DM);
        // g2 = gelu(A0@lin2) -> A2
        k_gemm_mfma<<<gg, 256, 0, stream>>>(A0, WB_lin2[i], lin2b + i * DM, 0, A2, DM, 1);
        if (i == 0) {
            k_gemm2_mfma<<<gg, 256, 0, stream>>>(A2, WB_head0, A1, WB_proj0,
                                                 headb[0], projb[0], A0, DM, 0);
        } else {
            dim3 gh(TOK / 64, 2 * DM / 64);
            k_gemm2_mfma<<<gh, 256, 0, stream>>>(A2, WB_head1, A1, WB_proj1,
                                                 headb[1], projb[1], F, 2 * DM, 8);
        }
    }
    {
        dim3 gf(LSEQ / 32, 2 * DM / 32, BSZ);
        dim3 bf(32, 8);
        k_final_out<<<gf, bf, 0, stream>>>(F, out);
    }
}